// Round 5
// baseline (2592.242 us; speedup 1.0000x reference)
//
#include <hip/hip_runtime.h>
#include <hip/hip_fp16.h>
#include <stdint.h>

#define TOKENS 8192
#define D_IN   4096
#define D_OUT  16384

#define BM 128
#define BN 128
#define BK 64

typedef unsigned short u16;
typedef _Float16 f16x8 __attribute__((ext_vector_type(8)));
typedef float f32x4 __attribute__((ext_vector_type(4)));

typedef const __attribute__((address_space(1))) void* gptr_t;
typedef __attribute__((address_space(3))) void* lptr_t;
#define GLDS16(g, l) __builtin_amdgcn_global_load_lds((gptr_t)(g), (lptr_t)(l), 16, 0, 0)

// ---------------- prep kernels: fp32 -> fp16 hi/lo split, sign(w) -> ±1 fp16 ----------------

__global__ __launch_bounds__(256) void prep_x_kernel(
    const float* __restrict__ x, u16* __restrict__ xhi, u16* __restrict__ xlo)
{
    const int n4 = TOKENS * D_IN / 4;
    const float4* x4 = (const float4*)x;
    ushort4* hi4 = (ushort4*)xhi;
    ushort4* lo4 = (ushort4*)xlo;
    int stride = gridDim.x * blockDim.x;
    for (int i = blockIdx.x * blockDim.x + threadIdx.x; i < n4; i += stride) {
        float4 v = x4[i];
        __half h0 = __float2half(v.x), h1 = __float2half(v.y),
               h2 = __float2half(v.z), h3 = __float2half(v.w);
        __half l0 = __float2half(v.x - __half2float(h0));
        __half l1 = __float2half(v.y - __half2float(h1));
        __half l2 = __float2half(v.z - __half2float(h2));
        __half l3 = __float2half(v.w - __half2float(h3));
        ushort4 h, l;
        h.x = __half_as_ushort(h0); h.y = __half_as_ushort(h1);
        h.z = __half_as_ushort(h2); h.w = __half_as_ushort(h3);
        l.x = __half_as_ushort(l0); l.y = __half_as_ushort(l1);
        l.z = __half_as_ushort(l2); l.w = __half_as_ushort(l3);
        hi4[i] = h;
        lo4[i] = l;
    }
}

__global__ __launch_bounds__(256) void prep_w_kernel(
    const float* __restrict__ w, u16* __restrict__ s)
{
    const int n4 = D_OUT * D_IN / 4;
    const float4* w4 = (const float4*)w;
    ushort4* s4 = (ushort4*)s;
    int stride = gridDim.x * blockDim.x;
    for (int i = blockIdx.x * blockDim.x + threadIdx.x; i < n4; i += stride) {
        float4 v = w4[i];
        ushort4 o;
        // sign with 0 -> +1 : only strictly-negative gets -1.0h (0xBC00)
        o.x = (v.x < 0.0f) ? 0xBC00u : 0x3C00u;
        o.y = (v.y < 0.0f) ? 0xBC00u : 0x3C00u;
        o.z = (v.z < 0.0f) ? 0xBC00u : 0x3C00u;
        o.w = (v.w < 0.0f) ? 0xBC00u : 0x3C00u;
        s4[i] = o;
    }
}

// ---------------- main GEMM: C = (xhi+xlo) @ sign^T, epilogue scale/bias ----------------
// m97 structure: 128x128 tile, BK=64, 4 waves (2x2 of 64x64), global_load_lds w=16,
// 2-barrier K-loop, 16x16x32 f16 MFMA, dual hi/lo accumulate into one acc.

__global__ __launch_bounds__(256, 2) void qat_gemm_kernel(
    const u16* __restrict__ xhi, const u16* __restrict__ xlo,
    const u16* __restrict__ wsg, const float* __restrict__ scale,
    const float* __restrict__ bias, float* __restrict__ out)
{
    __shared__ u16 sAhi[BM][BK];
    __shared__ u16 sAlo[BM][BK];
    __shared__ u16 sB [BN][BK];

    // XCD-aware swizzle (8192 % 8 == 0 -> simple form bijective) + 8-wide N supertile
    const int nwg = (TOKENS / BM) * (D_OUT / BN);   // 64*128 = 8192
    int bid = blockIdx.x;
    int wg = (bid & 7) * (nwg >> 3) + (bid >> 3);
    int super = wg / 512;            // 512 = 64 tm * 8 tn
    int rem   = wg % 512;
    int tm = rem >> 3;               // 0..63
    int tn = super * 8 + (rem & 7);  // 0..127

    const int tid  = threadIdx.x;
    const int lane = tid & 63;
    const int wid  = tid >> 6;       // 0..3
    const int wr = wid >> 1, wc = wid & 1;

    // staging map: per instruction a wave covers 8 rows x 64 cols (8 lanes/row * 16B)
    const int srow = lane >> 3;          // 0..7
    const int scol = (lane & 7) * 8;     // f16 element col within BK

    const size_t aRowBase = (size_t)tm * BM;
    const size_t bRowBase = (size_t)tn * BN;

    f32x4 acc[4][4];
    #pragma unroll
    for (int m = 0; m < 4; ++m)
        #pragma unroll
        for (int n = 0; n < 4; ++n)
            acc[m][n] = (f32x4){0.f, 0.f, 0.f, 0.f};

    const int frow = lane & 15;          // fragment row within 16
    const int fk   = (lane >> 4) * 8;    // fragment K sub-offset

    for (int kt = 0; kt < D_IN / BK; ++kt) {
        __syncthreads();   // previous iteration's ds_reads done before overwrite
        const int kcol = kt * BK + scol;
        #pragma unroll
        for (int i = 0; i < 4; ++i) {
            int r = wid * 32 + i * 8;     // wave-uniform LDS row base
            int grow = r + srow;          // per-lane global row
            GLDS16(xhi + (aRowBase + grow) * D_IN + kcol, &sAhi[r][0]);
            GLDS16(xlo + (aRowBase + grow) * D_IN + kcol, &sAlo[r][0]);
            GLDS16(wsg + (bRowBase + grow) * D_IN + kcol, &sB[r][0]);
        }
        __syncthreads();   // vmcnt drain: staged tile visible

        #pragma unroll
        for (int kk = 0; kk < 2; ++kk) {
            f16x8 ah[4], al[4], bv[4];
            #pragma unroll
            for (int m = 0; m < 4; ++m) {
                ah[m] = *(const f16x8*)&sAhi[wr * 64 + m * 16 + frow][kk * 32 + fk];
                al[m] = *(const f16x8*)&sAlo[wr * 64 + m * 16 + frow][kk * 32 + fk];
            }
            #pragma unroll
            for (int n = 0; n < 4; ++n)
                bv[n] = *(const f16x8*)&sB[wc * 64 + n * 16 + frow][kk * 32 + fk];
            #pragma unroll
            for (int m = 0; m < 4; ++m)
                #pragma unroll
                for (int n = 0; n < 4; ++n) {
                    acc[m][n] = __builtin_amdgcn_mfma_f32_16x16x32_f16(ah[m], bv[n], acc[m][n], 0, 0, 0);
                    acc[m][n] = __builtin_amdgcn_mfma_f32_16x16x32_f16(al[m], bv[n], acc[m][n], 0, 0, 0);
                }
        }
    }

    // epilogue: out = scale[col]*acc + bias[col]
    // C/D layout (m89/m91, dtype-independent): col = lane&15, row = (lane>>4)*4 + reg
    const int orow0 = tm * BM + wr * 64;
    const int ocol0 = tn * BN + wc * 64;
    #pragma unroll
    for (int n = 0; n < 4; ++n) {
        int col = ocol0 + n * 16 + (lane & 15);
        float sc = scale[col];
        float bb = bias[col];
        #pragma unroll
        for (int m = 0; m < 4; ++m) {
            int row = orow0 + m * 16 + (lane >> 4) * 4;
            #pragma unroll
            for (int r = 0; r < 4; ++r)
                out[(size_t)(row + r) * D_OUT + col] = sc * acc[m][n][r] + bb;
        }
    }
}

// ---------------- fallback (only if ws too small): tiled fp32 vector GEMM ----------------

__global__ __launch_bounds__(256) void qat_fallback_kernel(
    const float* __restrict__ x, const float* __restrict__ w,
    const float* __restrict__ scale, const float* __restrict__ b,
    float* __restrict__ out)
{
    __shared__ float sx[64][33];
    __shared__ float sw[64][33];
    const int tn = blockIdx.x % (D_OUT / 64);
    const int tm = blockIdx.x / (D_OUT / 64);
    const int tx = threadIdx.x & 15, ty = threadIdx.x >> 4;
    float acc[4][4] = {};
    for (int kt = 0; kt < D_IN; kt += 32) {
        #pragma unroll
        for (int i = 0; i < 8; ++i) {
            int idx = threadIdx.x + i * 256;
            int r = idx >> 5, c = idx & 31;
            sx[r][c] = x[(size_t)(tm * 64 + r) * D_IN + kt + c];
            float wv = w[(size_t)(tn * 64 + r) * D_IN + kt + c];
            sw[r][c] = (wv < 0.f) ? -1.f : 1.f;
        }
        __syncthreads();
        #pragma unroll 8
        for (int k = 0; k < 32; ++k)
            #pragma unroll
            for (int i = 0; i < 4; ++i)
                #pragma unroll
                for (int j = 0; j < 4; ++j)
                    acc[i][j] += sx[ty * 4 + i][k] * sw[tx * 4 + j][k];
        __syncthreads();
    }
    #pragma unroll
    for (int i = 0; i < 4; ++i) {
        int row = tm * 64 + ty * 4 + i;
        #pragma unroll
        for (int j = 0; j < 4; ++j) {
            int col = tn * 64 + tx * 4 + j;
            out[(size_t)row * D_OUT + col] = scale[col] * acc[i][j] + b[col];
        }
    }
}

// ---------------- host launcher ----------------

extern "C" void kernel_launch(void* const* d_in, const int* in_sizes, int n_in,
                              void* d_out, int out_size, void* d_ws, size_t ws_size,
                              hipStream_t stream)
{
    const float* x     = (const float*)d_in[0];
    const float* w     = (const float*)d_in[1];
    const float* scale = (const float*)d_in[2];
    const float* b     = (const float*)d_in[3];
    float* out = (float*)d_out;

    const size_t xhalf = (size_t)TOKENS * D_IN * sizeof(u16);   // 64 MB each
    const size_t wsgn  = (size_t)D_OUT * D_IN * sizeof(u16);    // 128 MB
    const size_t need  = 2 * xhalf + wsgn;                      // 256 MB

    if (d_ws != nullptr && ws_size >= need) {
        u16* xhi = (u16*)d_ws;
        u16* xlo = (u16*)((char*)d_ws + xhalf);
        u16* sg  = (u16*)((char*)d_ws + 2 * xhalf);
        prep_x_kernel<<<2048, 256, 0, stream>>>(x, xhi, xlo);
        prep_w_kernel<<<2048, 256, 0, stream>>>(w, sg);
        qat_gemm_kernel<<<(TOKENS / BM) * (D_OUT / BN), 256, 0, stream>>>(xhi, xlo, sg, scale, b, out);
    } else {
        qat_fallback_kernel<<<(TOKENS / 64) * (D_OUT / 64), 256, 0, stream>>>(x, w, scale, b, out);
    }
}

// Round 7
// 1693.606 us; speedup vs baseline: 1.5306x; 1.5306x over previous
//
#include <hip/hip_runtime.h>
#include <hip/hip_fp16.h>
#include <stdint.h>

#define TOKENS 8192
#define D_IN   4096
#define D_OUT  16384

#define BM 128
#define BN 128
#define BK 64

typedef unsigned short u16;
typedef _Float16 f16x8 __attribute__((ext_vector_type(8)));
typedef float f32x4 __attribute__((ext_vector_type(4)));

typedef const __attribute__((address_space(1))) void* gptr_t;
typedef __attribute__((address_space(3))) void* lptr_t;
#define GLDS16(g, l) __builtin_amdgcn_global_load_lds((gptr_t)(g), (lptr_t)(l), 16, 0, 0)

// ---------------- prep kernels: fp32 -> fp16 (hi only), sign(w) -> ±1 fp16 ----------------
// Accuracy: fp16 round-off 2^-11 rel per term; over K=4096 random-sign terms the
// output error max ≈ 0.08 abs vs tolerance 1.0 (measured round 5: hi/lo passed with
// absmax field = 1.0 -> tolerance). lo stream dropped: -50% MFMA work.

__global__ __launch_bounds__(256) void prep_x_kernel(
    const float* __restrict__ x, u16* __restrict__ xhi)
{
    const int n4 = TOKENS * D_IN / 4;
    const float4* x4 = (const float4*)x;
    ushort4* hi4 = (ushort4*)xhi;
    int stride = gridDim.x * blockDim.x;
    for (int i = blockIdx.x * blockDim.x + threadIdx.x; i < n4; i += stride) {
        float4 v = x4[i];
        ushort4 h;
        h.x = __half_as_ushort(__float2half(v.x));
        h.y = __half_as_ushort(__float2half(v.y));
        h.z = __half_as_ushort(__float2half(v.z));
        h.w = __half_as_ushort(__float2half(v.w));
        hi4[i] = h;
    }
}

__global__ __launch_bounds__(256) void prep_w_kernel(
    const float* __restrict__ w, u16* __restrict__ s)
{
    const int n4 = D_OUT * D_IN / 4;
    const float4* w4 = (const float4*)w;
    ushort4* s4 = (ushort4*)s;
    int stride = gridDim.x * blockDim.x;
    for (int i = blockIdx.x * blockDim.x + threadIdx.x; i < n4; i += stride) {
        float4 v = w4[i];
        ushort4 o;
        // sign with 0 -> +1 : only strictly-negative gets -1.0h (0xBC00)
        o.x = (v.x < 0.0f) ? 0xBC00u : 0x3C00u;
        o.y = (v.y < 0.0f) ? 0xBC00u : 0x3C00u;
        o.z = (v.z < 0.0f) ? 0xBC00u : 0x3C00u;
        o.w = (v.w < 0.0f) ? 0xBC00u : 0x3C00u;
        s4[i] = o;
    }
}

// ---------------- main GEMM: C = xhi @ sign^T, epilogue scale/bias ----------------
// m97 structure + T2 both-sides XOR swizzle (rule #21):
//   physical col8 = logical col8 ^ (row & 7)  (16B granularity)
//   - staging: linear LDS dest (global_load_lds requirement), INVERSE-swizzled
//     per-lane global source chunk: scol8 = (lane&7) ^ (lane>>3)
//   - ds_read: swizzled column pc8 = (kk*4 + lane>>4) ^ (row&7)
// Round 5 evidence: SQ_LDS_BANK_CONFLICT = 6.04e8/dispatch = ~47% of CU cycles
// from the un-swizzled 128B-row-stride fragment reads.

__global__ __launch_bounds__(256, 4) void qat_gemm_kernel(
    const u16* __restrict__ xhi, const u16* __restrict__ wsg,
    const float* __restrict__ scale, const float* __restrict__ bias,
    float* __restrict__ out)
{
    __shared__ u16 sA[BM][BK];
    __shared__ u16 sB[BN][BK];

    // XCD-aware swizzle (8192 % 8 == 0 -> bijective) + 8-wide N supertile
    const int nwg = (TOKENS / BM) * (D_OUT / BN);   // 8192
    int bid = blockIdx.x;
    int wg = (bid & 7) * (nwg >> 3) + (bid >> 3);
    int super = wg / 512;            // 512 = 64 tm * 8 tn
    int rem   = wg % 512;
    int tm = rem >> 3;               // 0..63
    int tn = super * 8 + (rem & 7);  // 0..127

    const int tid  = threadIdx.x;
    const int lane = tid & 63;
    const int wid  = tid >> 6;       // 0..3
    const int wr = wid >> 1, wc = wid & 1;

    // staging map: wave covers 8 rows x 64 cols per instruction (8 lanes/row * 16B)
    const int srow  = lane >> 3;                 // 0..7
    const int scol8 = (lane & 7) ^ srow;         // inverse-swizzled 16B chunk
    const int scol  = scol8 << 3;                // f16 element col within BK

    const size_t aRowBase = (size_t)tm * BM;
    const size_t bRowBase = (size_t)tn * BN;

    f32x4 acc[4][4];
    #pragma unroll
    for (int m = 0; m < 4; ++m)
        #pragma unroll
        for (int n = 0; n < 4; ++n)
            acc[m][n] = (f32x4){0.f, 0.f, 0.f, 0.f};

    const int frow = lane & 15;          // fragment row within 16
    const int q    = lane >> 4;          // K sub-chunk index 0..3

    for (int kt = 0; kt < D_IN / BK; ++kt) {
        __syncthreads();   // previous iteration's ds_reads done before overwrite
        const size_t kcol = (size_t)kt * BK + scol;
        #pragma unroll
        for (int i = 0; i < 4; ++i) {
            int r = wid * 32 + i * 8;     // wave-uniform LDS row base
            int grow = r + srow;          // per-lane global row
            GLDS16(xhi + (aRowBase + grow) * D_IN + kcol, &sA[r][0]);
            GLDS16(wsg + (bRowBase + grow) * D_IN + kcol, &sB[r][0]);
        }
        __syncthreads();   // vmcnt drain: staged tile visible

        #pragma unroll
        for (int kk = 0; kk < 2; ++kk) {
            f16x8 av[4], bv[4];
            #pragma unroll
            for (int m = 0; m < 4; ++m) {
                int R = wr * 64 + m * 16 + frow;
                int pc = ((kk * 4 + q) ^ (R & 7)) << 3;   // swizzled read col
                av[m] = *(const f16x8*)&sA[R][pc];
            }
            #pragma unroll
            for (int n = 0; n < 4; ++n) {
                int R = wc * 64 + n * 16 + frow;
                int pc = ((kk * 4 + q) ^ (R & 7)) << 3;
                bv[n] = *(const f16x8*)&sB[R][pc];
            }
            #pragma unroll
            for (int m = 0; m < 4; ++m)
                #pragma unroll
                for (int n = 0; n < 4; ++n)
                    acc[m][n] = __builtin_amdgcn_mfma_f32_16x16x32_f16(av[m], bv[n], acc[m][n], 0, 0, 0);
        }
    }

    // epilogue: out = scale[col]*acc + bias[col]
    // C/D layout (m89/m91): col = lane&15, row = (lane>>4)*4 + reg
    const int orow0 = tm * BM + wr * 64;
    const int ocol0 = tn * BN + wc * 64;
    #pragma unroll
    for (int n = 0; n < 4; ++n) {
        int col = ocol0 + n * 16 + (lane & 15);
        float sc = scale[col];
        float bb = bias[col];
        #pragma unroll
        for (int m = 0; m < 4; ++m) {
            int row = orow0 + m * 16 + (lane >> 4) * 4;
            #pragma unroll
            for (int r = 0; r < 4; ++r)
                out[(size_t)(row + r) * D_OUT + col] = sc * acc[m][n][r] + bb;
        }
    }
}

// ---------------- fallback (only if ws too small): tiled fp32 vector GEMM ----------------

__global__ __launch_bounds__(256) void qat_fallback_kernel(
    const float* __restrict__ x, const float* __restrict__ w,
    const float* __restrict__ scale, const float* __restrict__ b,
    float* __restrict__ out)
{
    __shared__ float sx[64][33];
    __shared__ float sw[64][33];
    const int tn = blockIdx.x % (D_OUT / 64);
    const int tm = blockIdx.x / (D_OUT / 64);
    const int tx = threadIdx.x & 15, ty = threadIdx.x >> 4;
    float acc[4][4] = {};
    for (int kt = 0; kt < D_IN; kt += 32) {
        #pragma unroll
        for (int i = 0; i < 8; ++i) {
            int idx = threadIdx.x + i * 256;
            int r = idx >> 5, c = idx & 31;
            sx[r][c] = x[(size_t)(tm * 64 + r) * D_IN + kt + c];
            float wv = w[(size_t)(tn * 64 + r) * D_IN + kt + c];
            sw[r][c] = (wv < 0.f) ? -1.f : 1.f;
        }
        __syncthreads();
        #pragma unroll 8
        for (int k = 0; k < 32; ++k)
            #pragma unroll
            for (int i = 0; i < 4; ++i)
                #pragma unroll
                for (int j = 0; j < 4; ++j)
                    acc[i][j] += sx[ty * 4 + i][k] * sw[tx * 4 + j][k];
        __syncthreads();
    }
    #pragma unroll
    for (int i = 0; i < 4; ++i) {
        int row = tm * 64 + ty * 4 + i;
        #pragma unroll
        for (int j = 0; j < 4; ++j) {
            int col = tn * 64 + tx * 4 + j;
            out[(size_t)row * D_OUT + col] = scale[col] * acc[i][j] + b[col];
        }
    }
}

// ---------------- host launcher ----------------

extern "C" void kernel_launch(void* const* d_in, const int* in_sizes, int n_in,
                              void* d_out, int out_size, void* d_ws, size_t ws_size,
                              hipStream_t stream)
{
    const float* x     = (const float*)d_in[0];
    const float* w     = (const float*)d_in[1];
    const float* scale = (const float*)d_in[2];
    const float* b     = (const float*)d_in[3];
    float* out = (float*)d_out;

    const size_t xhalf = (size_t)TOKENS * D_IN * sizeof(u16);   // 64 MB
    const size_t wsgn  = (size_t)D_OUT * D_IN * sizeof(u16);    // 128 MB
    const size_t need  = xhalf + wsgn;                          // 192 MB

    if (d_ws != nullptr && ws_size >= need) {
        u16* xhi = (u16*)d_ws;
        u16* sg  = (u16*)((char*)d_ws + xhalf);
        prep_x_kernel<<<2048, 256, 0, stream>>>(x, xhi);
        prep_w_kernel<<<2048, 256, 0, stream>>>(w, sg);
        qat_gemm_kernel<<<(TOKENS / BM) * (D_OUT / BN), 256, 0, stream>>>(xhi, sg, scale, b, out);
    } else {
        qat_fallback_kernel<<<(TOKENS / 64) * (D_OUT / 64), 256, 0, stream>>>(x, w, scale, b, out);
    }
}